// Round 1
// baseline (439.963 us; speedup 1.0000x reference)
//
#include <hip/hip_runtime.h>
#include <math.h>

#define NCLASSES   10000
#define NCLASSES4  2500            // NCLASSES / 4
#define NTHREADS   256
#define PER_THREAD 10              // ceil(2500 / 256)
#define IGNORE_INDEX (-1)

// smoothing constants
#define SMOOTH_UNIF 1e-5f          // SMOOTHING / CLASSES = 0.1 / 10000
#define SMOOTH_COMPL 0.9f          // 1 - SMOOTHING

__device__ __forceinline__ float blk_reduce_max(float v) {
    __shared__ float tmp[4];
    #pragma unroll
    for (int off = 32; off > 0; off >>= 1)
        v = fmaxf(v, __shfl_down(v, off, 64));
    int lane = threadIdx.x & 63, w = threadIdx.x >> 6;
    if (lane == 0) tmp[w] = v;
    __syncthreads();
    if (threadIdx.x == 0)
        tmp[0] = fmaxf(fmaxf(tmp[0], tmp[1]), fmaxf(tmp[2], tmp[3]));
    __syncthreads();
    v = tmp[0];
    __syncthreads();   // protect tmp against reuse by a later reduction
    return v;
}

__device__ __forceinline__ float blk_reduce_sum(float v) {
    __shared__ float tmp[4];
    #pragma unroll
    for (int off = 32; off > 0; off >>= 1)
        v += __shfl_down(v, off, 64);
    int lane = threadIdx.x & 63, w = threadIdx.x >> 6;
    if (lane == 0) tmp[w] = v;
    __syncthreads();
    if (threadIdx.x == 0)
        tmp[0] = tmp[0] + tmp[1] + tmp[2] + tmp[3];
    __syncthreads();
    v = tmp[0];
    __syncthreads();
    return v;
}

// One block per token row. Row (10000 fp32 = 40 KB) is held in registers:
// 10 float4 per thread. Single HBM pass over logits.
__global__ __launch_bounds__(NTHREADS)
void focal_ce_token_kernel(const float* __restrict__ logits,
                           const int* __restrict__ target,
                           float* __restrict__ tok_loss,
                           float* __restrict__ tok_mask) {
    const int row = blockIdx.x;
    const int t = threadIdx.x;
    const float* __restrict__ xrow = logits + (size_t)row * NCLASSES;
    const float4* __restrict__ xrow4 = reinterpret_cast<const float4*>(xrow);
    const int tgt = target[row];

    __shared__ float s_wt;         // focal term of the target class
    if (t == 0) s_wt = 0.0f;

    // ---- load row into registers, tracking max ----
    float4 v[PER_THREAD];
    float m = -INFINITY;
    #pragma unroll
    for (int i = 0; i < PER_THREAD; i++) {
        int idx4 = t + i * NTHREADS;
        if (idx4 < NCLASSES4) {
            v[i] = xrow4[idx4];
            m = fmaxf(m, fmaxf(fmaxf(v[i].x, v[i].y), fmaxf(v[i].z, v[i].w)));
        }
    }
    const float M = blk_reduce_max(m);

    // ---- sum of exp(x - M) ----
    float zsum = 0.0f;
    #pragma unroll
    for (int i = 0; i < PER_THREAD; i++) {
        int idx4 = t + i * NTHREADS;
        if (idx4 < NCLASSES4) {
            zsum += __expf(v[i].x - M);
            zsum += __expf(v[i].y - M);
            zsum += __expf(v[i].z - M);
            zsum += __expf(v[i].w - M);
        }
    }
    const float Z = blk_reduce_sum(zsum);
    const float lse = M + __logf(Z);

    // ---- focal-weighted sum: w_j = (1 - pt_j)^3 * logs_j ----
    float wsum = 0.0f;
    #pragma unroll
    for (int i = 0; i < PER_THREAD; i++) {
        int idx4 = t + i * NTHREADS;
        if (idx4 < NCLASSES4) {
            int j = 4 * idx4;
            {
                float ls = v[i].x - lse; float pt = __expf(ls);
                float om = 1.0f - pt;    float w = om * om * om * ls;
                wsum += w; if (j + 0 == tgt) s_wt = w;
            }
            {
                float ls = v[i].y - lse; float pt = __expf(ls);
                float om = 1.0f - pt;    float w = om * om * om * ls;
                wsum += w; if (j + 1 == tgt) s_wt = w;
            }
            {
                float ls = v[i].z - lse; float pt = __expf(ls);
                float om = 1.0f - pt;    float w = om * om * om * ls;
                wsum += w; if (j + 2 == tgt) s_wt = w;
            }
            {
                float ls = v[i].w - lse; float pt = __expf(ls);
                float om = 1.0f - pt;    float w = om * om * om * ls;
                wsum += w; if (j + 3 == tgt) s_wt = w;
            }
        }
    }
    const float W = blk_reduce_sum(wsum);   // contains a __syncthreads: s_wt visible

    if (t == 0) {
        if (tgt == IGNORE_INDEX) {
            tok_loss[row] = 0.0f;
            tok_mask[row] = 0.0f;
        } else {
            tok_loss[row] = -(SMOOTH_UNIF * W + SMOOTH_COMPL * s_wt);
            tok_mask[row] = 1.0f;
        }
    }
}

// Deterministic final reduce in double, single block.
__global__ __launch_bounds__(NTHREADS)
void finalize_kernel(const float* __restrict__ tok_loss,
                     const float* __restrict__ tok_mask,
                     float* __restrict__ out, int n_tok) {
    __shared__ double tmp_s[4], tmp_c[4];
    double s = 0.0, c = 0.0;
    for (int i = threadIdx.x; i < n_tok; i += NTHREADS) {
        s += (double)tok_loss[i];
        c += (double)tok_mask[i];
    }
    #pragma unroll
    for (int off = 32; off > 0; off >>= 1) {
        s += __shfl_down(s, off, 64);
        c += __shfl_down(c, off, 64);
    }
    int lane = threadIdx.x & 63, w = threadIdx.x >> 6;
    if (lane == 0) { tmp_s[w] = s; tmp_c[w] = c; }
    __syncthreads();
    if (threadIdx.x == 0) {
        double S = tmp_s[0] + tmp_s[1] + tmp_s[2] + tmp_s[3];
        double C = tmp_c[0] + tmp_c[1] + tmp_c[2] + tmp_c[3];
        out[0] = (float)(S / C);
    }
}

extern "C" void kernel_launch(void* const* d_in, const int* in_sizes, int n_in,
                              void* d_out, int out_size, void* d_ws, size_t ws_size,
                              hipStream_t stream) {
    const float* logits = (const float*)d_in[0];
    const int* target = (const int*)d_in[1];
    const int n_tok = in_sizes[1];          // B*S = 8192

    float* tok_loss = (float*)d_ws;
    float* tok_mask = tok_loss + n_tok;

    focal_ce_token_kernel<<<n_tok, NTHREADS, 0, stream>>>(logits, target, tok_loss, tok_mask);
    finalize_kernel<<<1, NTHREADS, 0, stream>>>(tok_loss, tok_mask, (float*)d_out, n_tok);
}

// Round 2
// 436.438 us; speedup vs baseline: 1.0081x; 1.0081x over previous
//
#include <hip/hip_runtime.h>
#include <math.h>

#define NCLASSES   10000
#define NCLASSES4  2500            // NCLASSES / 4
#define NT         512             // threads per block (8 waves)
#define PT         5               // float4 per thread: 512*5 = 2560 >= 2500
#define IGNORE_INDEX (-1)

#define SMOOTH_UNIF  1e-5f         // SMOOTHING / CLASSES
#define SMOOTH_COMPL 0.9f          // 1 - SMOOTHING

// ---- block reductions (8 waves); caller provides distinct LDS scratch so
// ---- consecutive reductions need no trailing barrier.
__device__ __forceinline__ float blk_max(float v, float* red) {
    #pragma unroll
    for (int off = 32; off > 0; off >>= 1)
        v = fmaxf(v, __shfl_down(v, off, 64));
    if ((threadIdx.x & 63) == 0) red[threadIdx.x >> 6] = v;
    __syncthreads();
    if (threadIdx.x == 0) {
        float r = red[0];
        #pragma unroll
        for (int j = 1; j < NT / 64; j++) r = fmaxf(r, red[j]);
        red[0] = r;
    }
    __syncthreads();
    return red[0];
}

__device__ __forceinline__ float blk_sum(float v, float* red) {
    #pragma unroll
    for (int off = 32; off > 0; off >>= 1)
        v += __shfl_down(v, off, 64);
    if ((threadIdx.x & 63) == 0) red[threadIdx.x >> 6] = v;
    __syncthreads();
    if (threadIdx.x == 0) {
        float r = red[0];
        #pragma unroll
        for (int j = 1; j < NT / 64; j++) r += red[j];
        red[0] = r;
    }
    __syncthreads();
    return red[0];
}

// One block per token row; row (40 KB) held in registers (5 float4/thread).
// Single HBM pass over logits.
__global__ __launch_bounds__(NT)
void focal_ce_token_kernel(const float* __restrict__ logits,
                           const int* __restrict__ target,
                           float* __restrict__ tok_loss,
                           float* __restrict__ tok_mask) {
    const int row = blockIdx.x;
    const int t = threadIdx.x;
    const float4* __restrict__ xrow4 =
        reinterpret_cast<const float4*>(logits + (size_t)row * NCLASSES);
    const int tgt = target[row];

    __shared__ float redA[NT / 64], redB[NT / 64], redC[NT / 64];
    __shared__ float s_xt;         // raw logit of the target class
    if (t == 0) s_xt = 0.0f;

    // ---- load row into registers, tracking max ----
    float4 v[PT];
    float m = -INFINITY;
    #pragma unroll
    for (int i = 0; i < PT; i++) {
        int idx4 = t + i * NT;
        if (idx4 < NCLASSES4) {
            v[i] = xrow4[idx4];
            m = fmaxf(m, fmaxf(fmaxf(v[i].x, v[i].y), fmaxf(v[i].z, v[i].w)));
        }
    }

    // ---- owner thread stashes the target logit (one compare per block,
    // ---- not four per element). Visible after blk_max's barrier.
    if (tgt >= 0) {
        const int idx4_t = tgt >> 2;               // target's float4 index
        if (t == (idx4_t & (NT - 1))) {            // owner: idx4_t % NT
            const int it = idx4_t >> 9;            // which v[i]: idx4_t / NT
            const int c = tgt & 3;
            float xt = 0.0f;
            #pragma unroll
            for (int i = 0; i < PT; i++)
                if (i == it)
                    xt = (c == 0) ? v[i].x : (c == 1) ? v[i].y
                       : (c == 2) ? v[i].z : v[i].w;
            s_xt = xt;
        }
    }

    const float M = blk_max(m, redA);

    // ---- sum of exp(x - M) ----
    float zs = 0.0f;
    #pragma unroll
    for (int i = 0; i < PT; i++) {
        int idx4 = t + i * NT;
        if (idx4 < NCLASSES4) {
            zs += __expf(v[i].x - M);
            zs += __expf(v[i].y - M);
            zs += __expf(v[i].z - M);
            zs += __expf(v[i].w - M);
        }
    }
    const float Z = blk_sum(zs, redB);
    const float lse = M + __logf(Z);

    // ---- focal-weighted sum: w_j = (1 - pt_j)^3 * logs_j ----
    float ws = 0.0f;
    #pragma unroll
    for (int i = 0; i < PT; i++) {
        int idx4 = t + i * NT;
        if (idx4 < NCLASSES4) {
            {
                float ls = v[i].x - lse; float pt = __expf(ls);
                float om = 1.0f - pt;    ws += om * om * om * ls;
            }
            {
                float ls = v[i].y - lse; float pt = __expf(ls);
                float om = 1.0f - pt;    ws += om * om * om * ls;
            }
            {
                float ls = v[i].z - lse; float pt = __expf(ls);
                float om = 1.0f - pt;    ws += om * om * om * ls;
            }
            {
                float ls = v[i].w - lse; float pt = __expf(ls);
                float om = 1.0f - pt;    ws += om * om * om * ls;
            }
        }
    }
    const float W = blk_sum(ws, redC);

    if (t == 0) {
        if (tgt == IGNORE_INDEX) {
            tok_loss[row] = 0.0f;
            tok_mask[row] = 0.0f;
        } else {
            float ls_t = s_xt - lse;
            float pt_t = __expf(ls_t);
            float om_t = 1.0f - pt_t;
            float w_t = om_t * om_t * om_t * ls_t;
            tok_loss[row] = -(SMOOTH_UNIF * W + SMOOTH_COMPL * w_t);
            tok_mask[row] = 1.0f;
        }
    }
}

// Deterministic final reduce in double, single block.
__global__ __launch_bounds__(256)
void finalize_kernel(const float* __restrict__ tok_loss,
                     const float* __restrict__ tok_mask,
                     float* __restrict__ out, int n_tok) {
    __shared__ double tmp_s[4], tmp_c[4];
    double s = 0.0, c = 0.0;
    for (int i = threadIdx.x; i < n_tok; i += 256) {
        s += (double)tok_loss[i];
        c += (double)tok_mask[i];
    }
    #pragma unroll
    for (int off = 32; off > 0; off >>= 1) {
        s += __shfl_down(s, off, 64);
        c += __shfl_down(c, off, 64);
    }
    int lane = threadIdx.x & 63, w = threadIdx.x >> 6;
    if (lane == 0) { tmp_s[w] = s; tmp_c[w] = c; }
    __syncthreads();
    if (threadIdx.x == 0) {
        double S = tmp_s[0] + tmp_s[1] + tmp_s[2] + tmp_s[3];
        double C = tmp_c[0] + tmp_c[1] + tmp_c[2] + tmp_c[3];
        out[0] = (float)(S / C);
    }
}

extern "C" void kernel_launch(void* const* d_in, const int* in_sizes, int n_in,
                              void* d_out, int out_size, void* d_ws, size_t ws_size,
                              hipStream_t stream) {
    const float* logits = (const float*)d_in[0];
    const int* target = (const int*)d_in[1];
    const int n_tok = in_sizes[1];          // B*S = 8192

    float* tok_loss = (float*)d_ws;
    float* tok_mask = tok_loss + n_tok;

    focal_ce_token_kernel<<<n_tok, NT, 0, stream>>>(logits, target, tok_loss, tok_mask);
    finalize_kernel<<<1, 256, 0, stream>>>(tok_loss, tok_mask, (float*)d_out, n_tok);
}